// Round 12
// baseline (150.649 us; speedup 1.0000x reference)
//
#include <hip/hip_runtime.h>

typedef unsigned short u16;
typedef unsigned int   u32;
typedef __bf16 bf16x8 __attribute__((ext_vector_type(8)));
typedef float  f32x4  __attribute__((ext_vector_type(4)));
typedef float  f32x16 __attribute__((ext_vector_type(16)));
typedef u32    u32x4  __attribute__((ext_vector_type(4)));

__device__ __forceinline__ u16 f2bf(float f) {
  u32 u = __builtin_bit_cast(u32, f);
  u += 0x7fffu + ((u >> 16) & 1u);   // RNE
  return (u16)(u >> 16);
}

#define GLOAD_LDS16(gptr, lptr)                                              \
  __builtin_amdgcn_global_load_lds(                                          \
      (const __attribute__((address_space(1))) void*)(gptr),                 \
      (__attribute__((address_space(3))) void*)(lptr), 16, 0, 0)

#define QK_FOLD 0.18033688011112042f   // 0.125 * log2(e): softmax in base-2

// ---------------------------------------------------------------- merged prep
// Regions by blockIdx.x (one launch instead of four serialized ones):
//   [0, 4096)        cast x -> bf16 (float4 per thread)
//   [4096, 7168)     transpose+cast Wqkv [1024][3072] -> [3072][1024] bf16
//   [7168, 8192)     transpose+cast Wproj [1024][1024] -> [1024][1024] bf16
//   [8192, 8448)     RoPE cos/sin table [2048][32] f32
__global__ __launch_bounds__(256) void prep_kernel(const float* __restrict__ x,
                                                   u16* __restrict__ xb,
                                                   const float* __restrict__ Wq,
                                                   u16* __restrict__ Wqt,
                                                   const float* __restrict__ Wp,
                                                   u16* __restrict__ Wpt,
                                                   float* __restrict__ cost,
                                                   float* __restrict__ sint) {
  __shared__ float tile[32][33];
  const int bid = blockIdx.x;
  if (bid < 4096) {
    const int i = bid * 256 + threadIdx.x;          // 1048576 = 4096*256 exact
    const float4 v = ((const float4*)x)[i];
    uint2 o;
    o.x = (u32)f2bf(v.x) | ((u32)f2bf(v.y) << 16);
    o.y = (u32)f2bf(v.z) | ((u32)f2bf(v.w) << 16);
    ((uint2*)xb)[i] = o;
  } else if (bid < 8192) {
    const bool isq = bid < 7168;
    const float* W = isq ? Wq : Wp;
    u16* Wt = isq ? Wqt : Wpt;
    const int t = isq ? (bid - 4096) : (bid - 7168);
    const int ntiles = isq ? 96 : 32;
    const int N = isq ? 3072 : 1024;
    const int k0 = (t / ntiles) * 32, n0 = (t % ntiles) * 32;
    const int tx = threadIdx.x & 31, ty = threadIdx.x >> 5;   // 32 x 8
#pragma unroll
    for (int i = 0; i < 32; i += 8)
      tile[ty + i][tx] = W[(size_t)(k0 + ty + i) * N + n0 + tx];
    __syncthreads();
#pragma unroll
    for (int i = 0; i < 32; i += 8)
      Wt[(size_t)(n0 + ty + i) * 1024 + k0 + tx] = f2bf(tile[tx][ty + i]);
  } else {
    const int idx = (bid - 8192) * 256 + threadIdx.x;   // 65536 = 2048 * 32
    const int s = idx >> 5, i = idx & 31;
    float inv = exp2f(-13.287712379549449f * (float)i * (1.0f / 32.0f));  // 10000^(-i/32)
    float sn, cs;
    sincosf((float)s * inv, &sn, &cs);
    cost[idx] = cs;
    sint[idx] = sn;
  }
}

// ---------------------------------------------------------------- QKV GEMM fused
// m97-structure GEMM (128x128, BK=64, gload_lds + swizzle) with fused epilogue:
//   bn 0..7  (q):  +bias, RoPE (table), *QK_FOLD -> qb [bh][s][64] bf16
//   bn 8..15 (k):  +bias, RoPE (table)           -> kb [bh][s][64] bf16
//   bn 16..23 (v): +bias, transpose              -> vt [bh][d][2048] bf16
__global__ __launch_bounds__(256) void gemm_qkv_rope_kernel(const u16* __restrict__ A,
                                                            const u16* __restrict__ Bt,
                                                            const float* __restrict__ bias,
                                                            const float* __restrict__ cost,
                                                            const float* __restrict__ sint,
                                                            u16* __restrict__ qb,
                                                            u16* __restrict__ kb,
                                                            u16* __restrict__ vt) {
  __shared__ u16 As[128][64];
  __shared__ u16 Bs[128][64];
  const int bm = blockIdx.y, bn = blockIdx.x;
  const int tid = threadIdx.x;
  const int wave = tid >> 6, lane = tid & 63;
  const int wr = wave >> 1, wc = wave & 1;
  const int l15 = lane & 15, lhi = lane >> 4;
  f32x4 acc[4][4] = {};
  const int K = 1024;

  const size_t arow0 = (size_t)bm * 128, brow0 = (size_t)bn * 128;
  const int srow_in = lane >> 3;
  const int sslot   = (lane & 7) ^ srow_in;

  for (int k0 = 0; k0 < K; k0 += 64) {
#pragma unroll
    for (int i = 0; i < 4; i++) {
      const int r = wave * 32 + i * 8 + srow_in;
      GLOAD_LDS16(A  + (arow0 + r) * K + k0 + sslot * 8, &As[wave * 32 + i * 8][0]);
      GLOAD_LDS16(Bt + (brow0 + r) * K + k0 + sslot * 8, &Bs[wave * 32 + i * 8][0]);
    }
    __syncthreads();

    bf16x8 af[4][2], bfr[4][2];
#pragma unroll
    for (int m = 0; m < 4; m++) {
      const int r = wr * 64 + m * 16 + l15;
#pragma unroll
      for (int kk = 0; kk < 2; kk++)
        af[m][kk] = *(const bf16x8*)(&As[0][0] + r * 64 + (((kk * 4 + lhi) ^ (r & 7)) * 8));
    }
#pragma unroll
    for (int n = 0; n < 4; n++) {
      const int r = wc * 64 + n * 16 + l15;
#pragma unroll
      for (int kk = 0; kk < 2; kk++)
        bfr[n][kk] = *(const bf16x8*)(&Bs[0][0] + r * 64 + (((kk * 4 + lhi) ^ (r & 7)) * 8));
    }
#pragma unroll
    for (int m = 0; m < 4; m++)
#pragma unroll
      for (int n = 0; n < 4; n++) {
        acc[m][n] = __builtin_amdgcn_mfma_f32_16x16x32_bf16(af[m][0], bfr[n][0], acc[m][n], 0, 0, 0);
        acc[m][n] = __builtin_amdgcn_mfma_f32_16x16x32_bf16(af[m][1], bfr[n][1], acc[m][n], 0, 0, 0);
      }
    __syncthreads();
  }

  float bv[4];
#pragma unroll
  for (int n = 0; n < 4; n++) bv[n] = bias[bn * 128 + wc * 64 + n * 16 + l15];

  if (bn < 16) {   // ---- q or k: bias + RoPE ----
    const bool isq = bn < 8;
    u16* dst = isq ? qb : kb;
    const int hcol = bn * 2 + wc - (isq ? 0 : 16);   // head 0..15
    const float fold = isq ? QK_FOLD : 1.0f;
#pragma unroll
    for (int m = 0; m < 4; m++)
#pragma unroll
      for (int r = 0; r < 4; r++) {
        const int row = bm * 128 + wr * 64 + m * 16 + lhi * 4 + r;
        const int b = row >> 11, s = row & 2047;
        const float cs0 = cost[s * 32 + l15],      sn0 = sint[s * 32 + l15];
        const float cs1 = cost[s * 32 + 16 + l15], sn1 = sint[s * 32 + 16 + l15];
        const float q0 = acc[m][0][r] + bv[0], q1 = acc[m][2][r] + bv[2];
        const float q2 = acc[m][1][r] + bv[1], q3 = acc[m][3][r] + bv[3];
        u16* orow = dst + ((size_t)(b * 16 + hcol) * 2048 + s) * 64;
        orow[l15]      = f2bf((q0 * cs0 - q1 * sn0) * fold);
        orow[l15 + 32] = f2bf((q1 * cs0 + q0 * sn0) * fold);
        orow[l15 + 16] = f2bf((q2 * cs1 - q3 * sn1) * fold);
        orow[l15 + 48] = f2bf((q3 * cs1 + q2 * sn1) * fold);
      }
  } else {         // ---- v: bias + transpose to [bh][d][2048] ----
    const int hcol = bn * 2 + wc - 32;               // head 0..15
    const int b = bm >> 4;
#pragma unroll
    for (int n = 0; n < 4; n++) {
      const int d = n * 16 + l15;
      u16* dcol = vt + ((size_t)(b * 16 + hcol) * 64 + d) * 2048;
#pragma unroll
      for (int m = 0; m < 4; m++) {
        const int s = (bm * 128 + wr * 64 + m * 16 + lhi * 4) & 2047;
        uint2 w;
        w.x = (u32)f2bf(acc[m][n][0] + bv[n]) | ((u32)f2bf(acc[m][n][1] + bv[n]) << 16);
        w.y = (u32)f2bf(acc[m][n][2] + bv[n]) | ((u32)f2bf(acc[m][n][3] + bv[n]) << 16);
        *(uint2*)(dcol + s) = w;
      }
    }
  }
}

// ---------------------------------------------------------------- proj GEMM, 64x128 tile
__global__ __launch_bounds__(256) void gemm_bias_m64_kernel(const u16* __restrict__ A,
                                                            const u16* __restrict__ Bt,
                                                            const float* __restrict__ bias,
                                                            float* __restrict__ C,
                                                            int M, int N, int K) {
  __shared__ u16 As[64][64];
  __shared__ u16 Bs[128][64];
  const int bm = blockIdx.y, bn = blockIdx.x;
  const int tid = threadIdx.x;
  const int wave = tid >> 6, lane = tid & 63;
  const int wr = wave >> 1, wc = wave & 1;
  const int l15 = lane & 15, lhi = lane >> 4;
  f32x4 acc[2][4] = {};

  const size_t arow0 = (size_t)bm * 64, brow0 = (size_t)bn * 128;
  const int srow_in = lane >> 3;
  const int sslot   = (lane & 7) ^ srow_in;

  for (int k0 = 0; k0 < K; k0 += 64) {
#pragma unroll
    for (int i = 0; i < 2; i++) {   // A: 64 rows, 2 issues/wave
      const int r = wave * 16 + i * 8 + srow_in;
      GLOAD_LDS16(A + (arow0 + r) * K + k0 + sslot * 8, &As[wave * 16 + i * 8][0]);
    }
#pragma unroll
    for (int i = 0; i < 4; i++) {   // B: 128 rows, 4 issues/wave
      const int r = wave * 32 + i * 8 + srow_in;
      GLOAD_LDS16(Bt + (brow0 + r) * K + k0 + sslot * 8, &Bs[wave * 32 + i * 8][0]);
    }
    __syncthreads();

    bf16x8 af[2][2], bfr[4][2];
#pragma unroll
    for (int m = 0; m < 2; m++) {
      const int r = wr * 32 + m * 16 + l15;
#pragma unroll
      for (int kk = 0; kk < 2; kk++)
        af[m][kk] = *(const bf16x8*)(&As[0][0] + r * 64 + (((kk * 4 + lhi) ^ (r & 7)) * 8));
    }
#pragma unroll
    for (int n = 0; n < 4; n++) {
      const int r = wc * 64 + n * 16 + l15;
#pragma unroll
      for (int kk = 0; kk < 2; kk++)
        bfr[n][kk] = *(const bf16x8*)(&Bs[0][0] + r * 64 + (((kk * 4 + lhi) ^ (r & 7)) * 8));
    }
#pragma unroll
    for (int m = 0; m < 2; m++)
#pragma unroll
      for (int n = 0; n < 4; n++) {
        acc[m][n] = __builtin_amdgcn_mfma_f32_16x16x32_bf16(af[m][0], bfr[n][0], acc[m][n], 0, 0, 0);
        acc[m][n] = __builtin_amdgcn_mfma_f32_16x16x32_bf16(af[m][1], bfr[n][1], acc[m][n], 0, 0, 0);
      }
    __syncthreads();
  }
#pragma unroll
  for (int n = 0; n < 4; n++) {
    int col = bn * 128 + wc * 64 + n * 16 + l15;
    float bvv = bias[col];
#pragma unroll
    for (int m = 0; m < 2; m++)
#pragma unroll
      for (int r = 0; r < 4; r++) {
        int row = bm * 64 + wr * 32 + m * 16 + lhi * 4 + r;
        C[(size_t)row * N + col] = acc[m][n][r] + bvv;
      }
  }
}

// ---------------------------------------------------------------- flash attention
// R10 structure verbatim (62.7 us validated: R6 staging + defer-max + VALU
// l_run) with ONE value-identical change: tree-shaped max (re-association of
// the fmax chain, depth 31 -> ~9). R11's lacc-via-MFMA form reverted (green
// parents, red child -> fragile-codegen zone; symptom was numerator/denominator
// defer-factor mismatch).
// WATCH: WRITE_SIZE must stay 8192 KB (spill detector).
__global__ __launch_bounds__(256) void flash_attn_kernel(const u16* __restrict__ qg,
                                                         const u16* __restrict__ kg,
                                                         const u16* __restrict__ vg,
                                                         u16* __restrict__ og) {
  __shared__ u16 Ks[2][64][64];
  __shared__ u16 Vs[2][64][64];
  const int hw = blockIdx.x;
  const int lb = (hw & 7) * 64 + (hw >> 3);      // XCD swizzle: 4 bh per XCD
  const int qt = lb & 15, bh = lb >> 4;
  const int b = bh >> 4, h = bh & 15;
  const int tid = threadIdx.x, wave = tid >> 6, lane = tid & 63;
  const int l5 = lane & 31, hi = lane >> 5;

  const u16* qrow = qg + ((size_t)bh * 2048 + qt * 128 + wave * 32 + l5) * 64 + hi * 8;
  bf16x8 qf[4];
#pragma unroll
  for (int kc = 0; kc < 4; kc++) qf[kc] = *(const bf16x8*)(qrow + kc * 16);

  f32x16 o[2] = {};
  float m_run = -1e30f, l_run = 0.f;

  const u16* gK = kg + (size_t)bh * 2048 * 64;
  const u16* gV = vg + (size_t)bh * 64 * 2048;
  const int srow0 = tid >> 3, sc16 = tid & 7;
  int4 kreg[2], vreg[2];

#pragma unroll
  for (int i = 0; i < 2; i++) {
    int r = srow0 + i * 32;
    kreg[i] = *(const int4*)(gK + (size_t)r * 64 + sc16 * 8);
    vreg[i] = *(const int4*)(gV + (size_t)r * 2048 + sc16 * 8);
  }
#pragma unroll
  for (int i = 0; i < 2; i++) {
    int r = srow0 + i * 32;
    int byo = r * 128 + ((sc16 * 16) ^ ((r & 7) << 4));
    *(int4*)((char*)&Ks[0][0][0] + byo) = kreg[i];
    *(int4*)((char*)&Vs[0][0][0] + byo) = vreg[i];
  }

  for (int kt = 0; kt < 32; kt++) {
    const int cur = kt & 1;
    __syncthreads();
    if (kt < 31) {
#pragma unroll
      for (int i = 0; i < 2; i++) {
        int r = srow0 + i * 32;
        kreg[i] = *(const int4*)(gK + ((size_t)(kt + 1) * 64 + r) * 64 + sc16 * 8);
        vreg[i] = *(const int4*)(gV + (size_t)r * 2048 + (kt + 1) * 64 + sc16 * 8);
      }
    }
    const char* KsB = (const char*)&Ks[cur][0][0];
    const char* VsB = (const char*)&Vs[cur][0][0];

    f32x16 sf[2];
#pragma unroll
    for (int k32 = 0; k32 < 2; k32++) {
      int r = k32 * 32 + l5;
      const char* rowp = KsB + r * 128;
      int sw = (r & 7) << 4;
      f32x16 s = {};
#pragma unroll
      for (int kc = 0; kc < 4; kc++) {
        bf16x8 kf = *(const bf16x8*)(rowp + ((kc * 32 + hi * 16) ^ sw));
        s = __builtin_amdgcn_mfma_f32_32x32x16_bf16(kf, qf[kc], s, 0, 0, 0);
      }
      sf[k32] = s;
    }

    // ---- online softmax (base-2), tree max + defer-max (T13) ----
    float t[16];
#pragma unroll
    for (int r = 0; r < 16; r++) t[r] = fmaxf(sf[0][r], sf[1][r]);
#pragma unroll
    for (int s2 = 8; s2 > 0; s2 >>= 1)
#pragma unroll
      for (int r = 0; r < 8; r++)
        if (r < s2) t[r] = fmaxf(t[r], t[r + s2]);
    float pmax = fmaxf(t[0], __shfl_xor(t[0], 32));

    if (!__all(pmax - m_run <= 11.541560327111707f)) {
      float mnew = fmaxf(m_run, pmax);
      float alpha = __builtin_amdgcn_exp2f(m_run - mnew);
      m_run = mnew;
      l_run *= alpha;
#pragma unroll
      for (int dc = 0; dc < 2; dc++)
#pragma unroll
        for (int r = 0; r < 16; r++) o[dc][r] *= alpha;
    }
    float rs = 0.f;
#pragma unroll
    for (int k32 = 0; k32 < 2; k32++)
#pragma unroll
      for (int r = 0; r < 16; r++) {
        float p = __builtin_amdgcn_exp2f(sf[k32][r] - m_run);
        sf[k32][r] = p;
        rs += p;
      }
    rs += __shfl_xor(rs, 32);
    l_run += rs;

    bf16x8 pf[4];
#pragma unroll
    for (int k32 = 0; k32 < 2; k32++) {
      u32 u[8];
#pragma unroll
      for (int m = 0; m < 8; m++) {
        u32 w;
        asm("v_cvt_pk_bf16_f32 %0, %1, %2" : "=v"(w) : "v"(sf[k32][2 * m]), "v"(sf[k32][2 * m + 1]));
        u[m] = w;
      }
      asm("v_permlane32_swap_b32 %0, %1" : "+v"(u[0]), "+v"(u[2]));
      asm("v_permlane32_swap_b32 %0, %1" : "+v"(u[1]), "+v"(u[3]));
      asm("v_permlane32_swap_b32 %0, %1" : "+v"(u[4]), "+v"(u[6]));
      asm("v_permlane32_swap_b32 %0, %1" : "+v"(u[5]), "+v"(u[7]));
      u32x4 w0 = {u[0], u[1], u[2], u[3]};
      u32x4 w1 = {u[4], u[5], u[6], u[7]};
      pf[k32 * 2]     = __builtin_bit_cast(bf16x8, w0);
      pf[k32 * 2 + 1] = __builtin_bit_cast(bf16x8, w1);
    }

#pragma unroll
    for (int dc = 0; dc < 2; dc++) {
      int r = dc * 32 + l5;
      const char* rowp = VsB + r * 128;
      int sw = (r & 7) << 4;
#pragma unroll
      for (int kc = 0; kc < 4; kc++) {
        bf16x8 vf = *(const bf16x8*)(rowp + ((kc * 32 + hi * 16) ^ sw));
        o[dc] = __builtin_amdgcn_mfma_f32_32x32x16_bf16(vf, pf[kc], o[dc], 0, 0, 0);
      }
    }

    if (kt < 31) {
#pragma unroll
      for (int i = 0; i < 2; i++) {
        int r = srow0 + i * 32;
        int byo = r * 128 + ((sc16 * 16) ^ ((r & 7) << 4));
        *(int4*)((char*)&Ks[cur ^ 1][0][0] + byo) = kreg[i];
        *(int4*)((char*)&Vs[cur ^ 1][0][0] + byo) = vreg[i];
      }
    }
  }

  float rinv = 1.0f / l_run;
  int qglob = qt * 128 + wave * 32 + l5;
  u16* orow = og + ((size_t)b * 2048 + qglob) * 1024 + h * 64;
#pragma unroll
  for (int dc = 0; dc < 2; dc++)
#pragma unroll
    for (int m = 0; m < 4; m++) {
      int d0 = dc * 32 + m * 8 + hi * 4;
      float a0 = o[dc][4 * m + 0] * rinv, a1 = o[dc][4 * m + 1] * rinv;
      float a2 = o[dc][4 * m + 2] * rinv, a3 = o[dc][4 * m + 3] * rinv;
      uint2 w;
      w.x = (u32)f2bf(a0) | ((u32)f2bf(a1) << 16);
      w.y = (u32)f2bf(a2) | ((u32)f2bf(a3) << 16);
      *(uint2*)(orow + d0) = w;
    }
}

// ---------------------------------------------------------------- launch
extern "C" void kernel_launch(void* const* d_in, const int* in_sizes, int n_in,
                              void* d_out, int out_size, void* d_ws, size_t ws_size,
                              hipStream_t stream) {
  const float* x     = (const float*)d_in[0];
  const float* Wqkv  = (const float*)d_in[1];
  const float* bqkv  = (const float*)d_in[2];
  const float* Wproj = (const float*)d_in[3];
  const float* bproj = (const float*)d_in[4];
  float* out = (float*)d_out;

  // workspace layout (<= 96 MB)
  char* ws = (char*)d_ws;
  u16*   xb    = (u16*)ws;                                   // 8 MB  [4096][1024]
  u16*   wqkvt = xb + (size_t)4096 * 1024;                   // 6 MB  [3072][1024]
  u16*   wprot = wqkvt + (size_t)3072 * 1024;                // 2 MB  [1024][1024]
  float* cost  = (float*)(ws + (size_t)16 * 1024 * 1024);    // 256 KB [2048][32]
  float* sint  = cost + 2048 * 32;                           // 256 KB
  u16*   qb2   = (u16*)(ws + (size_t)64 * 1024 * 1024);      // 8 MB  [32][2048][64]
  u16*   kb2   = (u16*)(ws + (size_t)72 * 1024 * 1024);      // 8 MB
  u16*   vtw   = (u16*)(ws + (size_t)80 * 1024 * 1024);      // 8 MB  [32][64][2048]
  u16*   obw   = (u16*)(ws + (size_t)88 * 1024 * 1024);      // 8 MB  [4096][1024]

  prep_kernel<<<dim3(8448), dim3(256), 0, stream>>>(x, xb, Wqkv, wqkvt, Wproj, wprot, cost, sint);
  gemm_qkv_rope_kernel<<<dim3(24, 32), dim3(256), 0, stream>>>(xb, wqkvt, bqkv, cost, sint,
                                                               qb2, kb2, vtw);
  flash_attn_kernel<<<dim3(512), dim3(256), 0, stream>>>(qb2, kb2, vtw, obw);
  gemm_bias_m64_kernel<<<dim3(8, 64), dim3(256), 0, stream>>>(obw, wprot, bproj, out, 4096, 1024, 1024);
}

// Round 13
// 128.102 us; speedup vs baseline: 1.1760x; 1.1760x over previous
//
#include <hip/hip_runtime.h>

typedef unsigned short u16;
typedef unsigned int   u32;
typedef __bf16 bf16x8 __attribute__((ext_vector_type(8)));
typedef float  f32x4  __attribute__((ext_vector_type(4)));
typedef float  f32x16 __attribute__((ext_vector_type(16)));
typedef u32    u32x4  __attribute__((ext_vector_type(4)));

__device__ __forceinline__ u16 f2bf(float f) {
  u32 u = __builtin_bit_cast(u32, f);
  u += 0x7fffu + ((u >> 16) & 1u);   // RNE
  return (u16)(u >> 16);
}

#define GLOAD_LDS16(gptr, lptr)                                              \
  __builtin_amdgcn_global_load_lds(                                          \
      (const __attribute__((address_space(1))) void*)(gptr),                 \
      (__attribute__((address_space(3))) void*)(lptr), 16, 0, 0)

#define QK_FOLD 0.18033688011112042f   // 0.125 * log2(e): softmax in base-2

// ---------------------------------------------------------------- merged prep
// Regions by blockIdx.x (one launch instead of four serialized ones):
//   [0, 4096)        cast x -> bf16 (float4 per thread)
//   [4096, 7168)     transpose+cast Wqkv [1024][3072] -> [3072][1024] bf16
//   [7168, 8192)     transpose+cast Wproj [1024][1024] -> [1024][1024] bf16
//   [8192, 8448)     RoPE cos/sin table [2048][32] f32
__global__ __launch_bounds__(256) void prep_kernel(const float* __restrict__ x,
                                                   u16* __restrict__ xb,
                                                   const float* __restrict__ Wq,
                                                   u16* __restrict__ Wqt,
                                                   const float* __restrict__ Wp,
                                                   u16* __restrict__ Wpt,
                                                   float* __restrict__ cost,
                                                   float* __restrict__ sint) {
  __shared__ float tile[32][33];
  const int bid = blockIdx.x;
  if (bid < 4096) {
    const int i = bid * 256 + threadIdx.x;          // 1048576 = 4096*256 exact
    const float4 v = ((const float4*)x)[i];
    uint2 o;
    o.x = (u32)f2bf(v.x) | ((u32)f2bf(v.y) << 16);
    o.y = (u32)f2bf(v.z) | ((u32)f2bf(v.w) << 16);
    ((uint2*)xb)[i] = o;
  } else if (bid < 8192) {
    const bool isq = bid < 7168;
    const float* W = isq ? Wq : Wp;
    u16* Wt = isq ? Wqt : Wpt;
    const int t = isq ? (bid - 4096) : (bid - 7168);
    const int ntiles = isq ? 96 : 32;
    const int N = isq ? 3072 : 1024;
    const int k0 = (t / ntiles) * 32, n0 = (t % ntiles) * 32;
    const int tx = threadIdx.x & 31, ty = threadIdx.x >> 5;   // 32 x 8
#pragma unroll
    for (int i = 0; i < 32; i += 8)
      tile[ty + i][tx] = W[(size_t)(k0 + ty + i) * N + n0 + tx];
    __syncthreads();
#pragma unroll
    for (int i = 0; i < 32; i += 8)
      Wt[(size_t)(n0 + ty + i) * 1024 + k0 + tx] = f2bf(tile[tx][ty + i]);
  } else {
    const int idx = (bid - 8192) * 256 + threadIdx.x;   // 65536 = 2048 * 32
    const int s = idx >> 5, i = idx & 31;
    float inv = exp2f(-13.287712379549449f * (float)i * (1.0f / 32.0f));  // 10000^(-i/32)
    float sn, cs;
    sincosf((float)s * inv, &sn, &cs);
    cost[idx] = cs;
    sint[idx] = sn;
  }
}

// ---------------------------------------------------------------- QKV GEMM fused
// m97-structure GEMM (128x128, BK=64, gload_lds + swizzle) with fused epilogue:
//   bn 0..7  (q):  +bias, RoPE (table), *QK_FOLD -> qb [bh][s][64] bf16
//   bn 8..15 (k):  +bias, RoPE (table)           -> kb [bh][s][64] bf16
//   bn 16..23 (v): +bias, transpose              -> vt [bh][d][2048] bf16
__global__ __launch_bounds__(256) void gemm_qkv_rope_kernel(const u16* __restrict__ A,
                                                            const u16* __restrict__ Bt,
                                                            const float* __restrict__ bias,
                                                            const float* __restrict__ cost,
                                                            const float* __restrict__ sint,
                                                            u16* __restrict__ qb,
                                                            u16* __restrict__ kb,
                                                            u16* __restrict__ vt) {
  __shared__ u16 As[128][64];
  __shared__ u16 Bs[128][64];
  const int bm = blockIdx.y, bn = blockIdx.x;
  const int tid = threadIdx.x;
  const int wave = tid >> 6, lane = tid & 63;
  const int wr = wave >> 1, wc = wave & 1;
  const int l15 = lane & 15, lhi = lane >> 4;
  f32x4 acc[4][4] = {};
  const int K = 1024;

  const size_t arow0 = (size_t)bm * 128, brow0 = (size_t)bn * 128;
  const int srow_in = lane >> 3;
  const int sslot   = (lane & 7) ^ srow_in;

  for (int k0 = 0; k0 < K; k0 += 64) {
#pragma unroll
    for (int i = 0; i < 4; i++) {
      const int r = wave * 32 + i * 8 + srow_in;
      GLOAD_LDS16(A  + (arow0 + r) * K + k0 + sslot * 8, &As[wave * 32 + i * 8][0]);
      GLOAD_LDS16(Bt + (brow0 + r) * K + k0 + sslot * 8, &Bs[wave * 32 + i * 8][0]);
    }
    __syncthreads();

    bf16x8 af[4][2], bfr[4][2];
#pragma unroll
    for (int m = 0; m < 4; m++) {
      const int r = wr * 64 + m * 16 + l15;
#pragma unroll
      for (int kk = 0; kk < 2; kk++)
        af[m][kk] = *(const bf16x8*)(&As[0][0] + r * 64 + (((kk * 4 + lhi) ^ (r & 7)) * 8));
    }
#pragma unroll
    for (int n = 0; n < 4; n++) {
      const int r = wc * 64 + n * 16 + l15;
#pragma unroll
      for (int kk = 0; kk < 2; kk++)
        bfr[n][kk] = *(const bf16x8*)(&Bs[0][0] + r * 64 + (((kk * 4 + lhi) ^ (r & 7)) * 8));
    }
#pragma unroll
    for (int m = 0; m < 4; m++)
#pragma unroll
      for (int n = 0; n < 4; n++) {
        acc[m][n] = __builtin_amdgcn_mfma_f32_16x16x32_bf16(af[m][0], bfr[n][0], acc[m][n], 0, 0, 0);
        acc[m][n] = __builtin_amdgcn_mfma_f32_16x16x32_bf16(af[m][1], bfr[n][1], acc[m][n], 0, 0, 0);
      }
    __syncthreads();
  }

  float bv[4];
#pragma unroll
  for (int n = 0; n < 4; n++) bv[n] = bias[bn * 128 + wc * 64 + n * 16 + l15];

  if (bn < 16) {   // ---- q or k: bias + RoPE ----
    const bool isq = bn < 8;
    u16* dst = isq ? qb : kb;
    const int hcol = bn * 2 + wc - (isq ? 0 : 16);   // head 0..15
    const float fold = isq ? QK_FOLD : 1.0f;
#pragma unroll
    for (int m = 0; m < 4; m++)
#pragma unroll
      for (int r = 0; r < 4; r++) {
        const int row = bm * 128 + wr * 64 + m * 16 + lhi * 4 + r;
        const int b = row >> 11, s = row & 2047;
        const float cs0 = cost[s * 32 + l15],      sn0 = sint[s * 32 + l15];
        const float cs1 = cost[s * 32 + 16 + l15], sn1 = sint[s * 32 + 16 + l15];
        const float q0 = acc[m][0][r] + bv[0], q1 = acc[m][2][r] + bv[2];
        const float q2 = acc[m][1][r] + bv[1], q3 = acc[m][3][r] + bv[3];
        u16* orow = dst + ((size_t)(b * 16 + hcol) * 2048 + s) * 64;
        orow[l15]      = f2bf((q0 * cs0 - q1 * sn0) * fold);
        orow[l15 + 32] = f2bf((q1 * cs0 + q0 * sn0) * fold);
        orow[l15 + 16] = f2bf((q2 * cs1 - q3 * sn1) * fold);
        orow[l15 + 48] = f2bf((q3 * cs1 + q2 * sn1) * fold);
      }
  } else {         // ---- v: bias + transpose to [bh][d][2048] ----
    const int hcol = bn * 2 + wc - 32;               // head 0..15
    const int b = bm >> 4;
#pragma unroll
    for (int n = 0; n < 4; n++) {
      const int d = n * 16 + l15;
      u16* dcol = vt + ((size_t)(b * 16 + hcol) * 64 + d) * 2048;
#pragma unroll
      for (int m = 0; m < 4; m++) {
        const int s = (bm * 128 + wr * 64 + m * 16 + lhi * 4) & 2047;
        uint2 w;
        w.x = (u32)f2bf(acc[m][n][0] + bv[n]) | ((u32)f2bf(acc[m][n][1] + bv[n]) << 16);
        w.y = (u32)f2bf(acc[m][n][2] + bv[n]) | ((u32)f2bf(acc[m][n][3] + bv[n]) << 16);
        *(uint2*)(dcol + s) = w;
      }
    }
  }
}

// ---------------------------------------------------------------- proj GEMM, 64x128 tile
__global__ __launch_bounds__(256) void gemm_bias_m64_kernel(const u16* __restrict__ A,
                                                            const u16* __restrict__ Bt,
                                                            const float* __restrict__ bias,
                                                            float* __restrict__ C,
                                                            int M, int N, int K) {
  __shared__ u16 As[64][64];
  __shared__ u16 Bs[128][64];
  const int bm = blockIdx.y, bn = blockIdx.x;
  const int tid = threadIdx.x;
  const int wave = tid >> 6, lane = tid & 63;
  const int wr = wave >> 1, wc = wave & 1;
  const int l15 = lane & 15, lhi = lane >> 4;
  f32x4 acc[2][4] = {};

  const size_t arow0 = (size_t)bm * 64, brow0 = (size_t)bn * 128;
  const int srow_in = lane >> 3;
  const int sslot   = (lane & 7) ^ srow_in;

  for (int k0 = 0; k0 < K; k0 += 64) {
#pragma unroll
    for (int i = 0; i < 2; i++) {   // A: 64 rows, 2 issues/wave
      const int r = wave * 16 + i * 8 + srow_in;
      GLOAD_LDS16(A + (arow0 + r) * K + k0 + sslot * 8, &As[wave * 16 + i * 8][0]);
    }
#pragma unroll
    for (int i = 0; i < 4; i++) {   // B: 128 rows, 4 issues/wave
      const int r = wave * 32 + i * 8 + srow_in;
      GLOAD_LDS16(Bt + (brow0 + r) * K + k0 + sslot * 8, &Bs[wave * 32 + i * 8][0]);
    }
    __syncthreads();

    bf16x8 af[2][2], bfr[4][2];
#pragma unroll
    for (int m = 0; m < 2; m++) {
      const int r = wr * 32 + m * 16 + l15;
#pragma unroll
      for (int kk = 0; kk < 2; kk++)
        af[m][kk] = *(const bf16x8*)(&As[0][0] + r * 64 + (((kk * 4 + lhi) ^ (r & 7)) * 8));
    }
#pragma unroll
    for (int n = 0; n < 4; n++) {
      const int r = wc * 64 + n * 16 + l15;
#pragma unroll
      for (int kk = 0; kk < 2; kk++)
        bfr[n][kk] = *(const bf16x8*)(&Bs[0][0] + r * 64 + (((kk * 4 + lhi) ^ (r & 7)) * 8));
    }
#pragma unroll
    for (int m = 0; m < 2; m++)
#pragma unroll
      for (int n = 0; n < 4; n++) {
        acc[m][n] = __builtin_amdgcn_mfma_f32_16x16x32_bf16(af[m][0], bfr[n][0], acc[m][n], 0, 0, 0);
        acc[m][n] = __builtin_amdgcn_mfma_f32_16x16x32_bf16(af[m][1], bfr[n][1], acc[m][n], 0, 0, 0);
      }
    __syncthreads();
  }
#pragma unroll
  for (int n = 0; n < 4; n++) {
    int col = bn * 128 + wc * 64 + n * 16 + l15;
    float bvv = bias[col];
#pragma unroll
    for (int m = 0; m < 2; m++)
#pragma unroll
      for (int r = 0; r < 4; r++) {
        int row = bm * 64 + wr * 32 + m * 16 + lhi * 4 + r;
        C[(size_t)row * N + col] = acc[m][n][r] + bvv;
      }
  }
}

// ---------------------------------------------------------------- flash attention
// R10 flash VERBATIM (62.7 us validated): R6 staging + serial chain max +
// defer-max (T13) + VALU l_run. R12's tree-max reverted — the t[16] temp
// array widened the peak live set and spilled (WRITE_SIZE 8192->16424 KB,
// flash 62.7->88.4). The 31-deep fmax chain reusing ONE register is the
// register-frugal form; keep it.
// WATCH: WRITE_SIZE must stay 8192 KB (spill detector).
__global__ __launch_bounds__(256) void flash_attn_kernel(const u16* __restrict__ qg,
                                                         const u16* __restrict__ kg,
                                                         const u16* __restrict__ vg,
                                                         u16* __restrict__ og) {
  __shared__ u16 Ks[2][64][64];
  __shared__ u16 Vs[2][64][64];
  const int hw = blockIdx.x;
  const int lb = (hw & 7) * 64 + (hw >> 3);      // XCD swizzle: 4 bh per XCD
  const int qt = lb & 15, bh = lb >> 4;
  const int b = bh >> 4, h = bh & 15;
  const int tid = threadIdx.x, wave = tid >> 6, lane = tid & 63;
  const int l5 = lane & 31, hi = lane >> 5;

  const u16* qrow = qg + ((size_t)bh * 2048 + qt * 128 + wave * 32 + l5) * 64 + hi * 8;
  bf16x8 qf[4];
#pragma unroll
  for (int kc = 0; kc < 4; kc++) qf[kc] = *(const bf16x8*)(qrow + kc * 16);

  f32x16 o[2] = {};
  float m_run = -1e30f, l_run = 0.f;

  const u16* gK = kg + (size_t)bh * 2048 * 64;
  const u16* gV = vg + (size_t)bh * 64 * 2048;
  const int srow0 = tid >> 3, sc16 = tid & 7;
  int4 kreg[2], vreg[2];

#pragma unroll
  for (int i = 0; i < 2; i++) {
    int r = srow0 + i * 32;
    kreg[i] = *(const int4*)(gK + (size_t)r * 64 + sc16 * 8);
    vreg[i] = *(const int4*)(gV + (size_t)r * 2048 + sc16 * 8);
  }
#pragma unroll
  for (int i = 0; i < 2; i++) {
    int r = srow0 + i * 32;
    int byo = r * 128 + ((sc16 * 16) ^ ((r & 7) << 4));
    *(int4*)((char*)&Ks[0][0][0] + byo) = kreg[i];
    *(int4*)((char*)&Vs[0][0][0] + byo) = vreg[i];
  }

  for (int kt = 0; kt < 32; kt++) {
    const int cur = kt & 1;
    __syncthreads();
    if (kt < 31) {
#pragma unroll
      for (int i = 0; i < 2; i++) {
        int r = srow0 + i * 32;
        kreg[i] = *(const int4*)(gK + ((size_t)(kt + 1) * 64 + r) * 64 + sc16 * 8);
        vreg[i] = *(const int4*)(gV + (size_t)r * 2048 + (kt + 1) * 64 + sc16 * 8);
      }
    }
    const char* KsB = (const char*)&Ks[cur][0][0];
    const char* VsB = (const char*)&Vs[cur][0][0];

    f32x16 sf[2];
#pragma unroll
    for (int k32 = 0; k32 < 2; k32++) {
      int r = k32 * 32 + l5;
      const char* rowp = KsB + r * 128;
      int sw = (r & 7) << 4;
      f32x16 s = {};
#pragma unroll
      for (int kc = 0; kc < 4; kc++) {
        bf16x8 kf = *(const bf16x8*)(rowp + ((kc * 32 + hi * 16) ^ sw));
        s = __builtin_amdgcn_mfma_f32_32x32x16_bf16(kf, qf[kc], s, 0, 0, 0);
      }
      sf[k32] = s;
    }

    // ---- online softmax (base-2), chain max + defer-max (T13) ----
    float pmax = sf[0][0];
#pragma unroll
    for (int r = 1; r < 16; r++) pmax = fmaxf(pmax, sf[0][r]);
#pragma unroll
    for (int r = 0; r < 16; r++) pmax = fmaxf(pmax, sf[1][r]);
    pmax = fmaxf(pmax, __shfl_xor(pmax, 32));

    if (!__all(pmax - m_run <= 11.541560327111707f)) {
      float mnew = fmaxf(m_run, pmax);
      float alpha = __builtin_amdgcn_exp2f(m_run - mnew);
      m_run = mnew;
      l_run *= alpha;
#pragma unroll
      for (int dc = 0; dc < 2; dc++)
#pragma unroll
        for (int r = 0; r < 16; r++) o[dc][r] *= alpha;
    }
    float rs = 0.f;
#pragma unroll
    for (int k32 = 0; k32 < 2; k32++)
#pragma unroll
      for (int r = 0; r < 16; r++) {
        float p = __builtin_amdgcn_exp2f(sf[k32][r] - m_run);
        sf[k32][r] = p;
        rs += p;
      }
    rs += __shfl_xor(rs, 32);
    l_run += rs;

    bf16x8 pf[4];
#pragma unroll
    for (int k32 = 0; k32 < 2; k32++) {
      u32 u[8];
#pragma unroll
      for (int m = 0; m < 8; m++) {
        u32 w;
        asm("v_cvt_pk_bf16_f32 %0, %1, %2" : "=v"(w) : "v"(sf[k32][2 * m]), "v"(sf[k32][2 * m + 1]));
        u[m] = w;
      }
      asm("v_permlane32_swap_b32 %0, %1" : "+v"(u[0]), "+v"(u[2]));
      asm("v_permlane32_swap_b32 %0, %1" : "+v"(u[1]), "+v"(u[3]));
      asm("v_permlane32_swap_b32 %0, %1" : "+v"(u[4]), "+v"(u[6]));
      asm("v_permlane32_swap_b32 %0, %1" : "+v"(u[5]), "+v"(u[7]));
      u32x4 w0 = {u[0], u[1], u[2], u[3]};
      u32x4 w1 = {u[4], u[5], u[6], u[7]};
      pf[k32 * 2]     = __builtin_bit_cast(bf16x8, w0);
      pf[k32 * 2 + 1] = __builtin_bit_cast(bf16x8, w1);
    }

#pragma unroll
    for (int dc = 0; dc < 2; dc++) {
      int r = dc * 32 + l5;
      const char* rowp = VsB + r * 128;
      int sw = (r & 7) << 4;
#pragma unroll
      for (int kc = 0; kc < 4; kc++) {
        bf16x8 vf = *(const bf16x8*)(rowp + ((kc * 32 + hi * 16) ^ sw));
        o[dc] = __builtin_amdgcn_mfma_f32_32x32x16_bf16(vf, pf[kc], o[dc], 0, 0, 0);
      }
    }

    if (kt < 31) {
#pragma unroll
      for (int i = 0; i < 2; i++) {
        int r = srow0 + i * 32;
        int byo = r * 128 + ((sc16 * 16) ^ ((r & 7) << 4));
        *(int4*)((char*)&Ks[cur ^ 1][0][0] + byo) = kreg[i];
        *(int4*)((char*)&Vs[cur ^ 1][0][0] + byo) = vreg[i];
      }
    }
  }

  float rinv = 1.0f / l_run;
  int qglob = qt * 128 + wave * 32 + l5;
  u16* orow = og + ((size_t)b * 2048 + qglob) * 1024 + h * 64;
#pragma unroll
  for (int dc = 0; dc < 2; dc++)
#pragma unroll
    for (int m = 0; m < 4; m++) {
      int d0 = dc * 32 + m * 8 + hi * 4;
      float a0 = o[dc][4 * m + 0] * rinv, a1 = o[dc][4 * m + 1] * rinv;
      float a2 = o[dc][4 * m + 2] * rinv, a3 = o[dc][4 * m + 3] * rinv;
      uint2 w;
      w.x = (u32)f2bf(a0) | ((u32)f2bf(a1) << 16);
      w.y = (u32)f2bf(a2) | ((u32)f2bf(a3) << 16);
      *(uint2*)(orow + d0) = w;
    }
}

// ---------------------------------------------------------------- launch
extern "C" void kernel_launch(void* const* d_in, const int* in_sizes, int n_in,
                              void* d_out, int out_size, void* d_ws, size_t ws_size,
                              hipStream_t stream) {
  const float* x     = (const float*)d_in[0];
  const float* Wqkv  = (const float*)d_in[1];
  const float* bqkv  = (const float*)d_in[2];
  const float* Wproj = (const float*)d_in[3];
  const float* bproj = (const float*)d_in[4];
  float* out = (float*)d_out;

  // workspace layout (<= 96 MB)
  char* ws = (char*)d_ws;
  u16*   xb    = (u16*)ws;                                   // 8 MB  [4096][1024]
  u16*   wqkvt = xb + (size_t)4096 * 1024;                   // 6 MB  [3072][1024]
  u16*   wprot = wqkvt + (size_t)3072 * 1024;                // 2 MB  [1024][1024]
  float* cost  = (float*)(ws + (size_t)16 * 1024 * 1024);    // 256 KB [2048][32]
  float* sint  = cost + 2048 * 32;                           // 256 KB
  u16*   qb2   = (u16*)(ws + (size_t)64 * 1024 * 1024);      // 8 MB  [32][2048][64]
  u16*   kb2   = (u16*)(ws + (size_t)72 * 1024 * 1024);      // 8 MB
  u16*   vtw   = (u16*)(ws + (size_t)80 * 1024 * 1024);      // 8 MB  [32][64][2048]
  u16*   obw   = (u16*)(ws + (size_t)88 * 1024 * 1024);      // 8 MB  [4096][1024]

  prep_kernel<<<dim3(8448), dim3(256), 0, stream>>>(x, xb, Wqkv, wqkvt, Wproj, wprot, cost, sint);
  gemm_qkv_rope_kernel<<<dim3(24, 32), dim3(256), 0, stream>>>(xb, wqkvt, bqkv, cost, sint,
                                                               qb2, kb2, vtw);
  flash_attn_kernel<<<dim3(512), dim3(256), 0, stream>>>(qb2, kb2, vtw, obw);
  gemm_bias_m64_kernel<<<dim3(8, 64), dim3(256), 0, stream>>>(obw, wprot, bproj, out, 4096, 1024, 1024);
}